// Round 14
// baseline (1378.303 us; speedup 1.0000x reference)
//
#include <hip/hip_runtime.h>
#include <math.h>

#define B_   128
#define L_   256
#define DW_  100
#define DC_  30
#define HD_  200
#define NT_  18
#define SG   4     // batches per scan block (v10 proven config)
#define KP0  160   // padded K for layer-0 GEMM (130 -> 160)
#define KP1  416   // padded K for layer-1 GEMM (400 -> 416)
#define WLP  424   // wlB pitch in halves (16B-aligned, 8-bank spread)

typedef _Float16 half8 __attribute__((ext_vector_type(8)));
typedef _Float16 half4 __attribute__((ext_vector_type(4)));
typedef float    f32x4 __attribute__((ext_vector_type(4)));

__device__ __forceinline__ float frcp_(float x) { return __builtin_amdgcn_rcpf(x); }
__device__ __forceinline__ float sigm_(float x) { return frcp_(1.0f + __expf(-x)); }
__device__ __forceinline__ float tanh_(float x) { return 1.0f - 2.0f * frcp_(1.0f + __expf(2.0f * x)); }

// barrier that does NOT drain vmcnt: LDS visibility only.
__device__ __forceinline__ void barrier_lgkm() {
    asm volatile("s_waitcnt lgkmcnt(0)" ::: "memory");
    __builtin_amdgcn_s_barrier();
    asm volatile("" ::: "memory");
}

// ---------------- seq_len rank sort -> perm (ascending), one block
__global__ __launch_bounds__(128) void k_sortperm(const int* __restrict__ seq_len,
                                                  int* __restrict__ perm) {
    __shared__ int s[B_];
    int i = threadIdx.x;
    s[i] = seq_len[i];
    __syncthreads();
    int key = s[i], r = 0;
    for (int j = 0; j < B_; j++) {
        int v = s[j];
        r += (v < key) || (v == key && j < i);
    }
    perm[r] = i;
}

// ---------------- embedding gather -> fp16 x (B*L, KP0), pads zeroed
__global__ void k_embed(const int* __restrict__ words, const int* __restrict__ caps,
                        const float* __restrict__ wemb, const float* __restrict__ cemb,
                        _Float16* __restrict__ x) {
    int pos = blockIdx.x;
    int w = words[pos], c = caps[pos];
    _Float16* xp = x + (size_t)pos * KP0;
    for (int t = threadIdx.x; t < KP0; t += blockDim.x) {
        float v = 0.f;
        if (t < DW_) v = wemb[(size_t)w * DW_ + t];
        else if (t < DW_ + DC_) v = cemb[(size_t)c * DC_ + (t - DW_)];
        xp[t] = (_Float16)v;
    }
}

// ---------------- fused W_ih prep for all 4 (layer,dir) weight blocks.
#define N_L0 (800 * KP0)     // per-direction element count, layer 0
#define N_L1 (800 * KP1)     // per-direction element count, layer 1
__global__ void k_prep_wih(const float* __restrict__ Wih0f, const float* __restrict__ Wih0b,
                           const float* __restrict__ Wih1f, const float* __restrict__ Wih1b,
                           _Float16* __restrict__ wihT0, _Float16* __restrict__ wihT1) {
    int i = blockIdx.x * blockDim.x + threadIdx.x;
    const float* src;
    _Float16* dst;
    int K, Kpad, colOff, idx;
    if (i < 2 * N_L0) {
        int which = i / N_L0;            // 0 = fwd, 1 = bwd
        idx = i - which * N_L0;
        src = which ? Wih0b : Wih0f;
        dst = wihT0; K = 130; Kpad = KP0; colOff = which * 800;
    } else {
        int j = i - 2 * N_L0;
        if (j >= 2 * N_L1) return;
        int which = j / N_L1;
        idx = j - which * N_L1;
        src = which ? Wih1b : Wih1f;
        dst = wihT1; K = 400; Kpad = KP1; colOff = which * 800;
    }
    int r = idx / Kpad, k = idx - r * Kpad;
    int jh = r % 200, g = r / 200;
    int col = colOff + (jh << 2) + g;
    dst[(size_t)col * Kpad + k] = (k < K) ? (_Float16)src[(size_t)r * K + k] : (_Float16)0.f;
}

// ---------------- fused small prep: bias0, bias1, wlB, blog in one launch.
__global__ void k_prep_small(const float* __restrict__ bi0f, const float* __restrict__ bh0f,
                             const float* __restrict__ bi0b, const float* __restrict__ bh0b,
                             const float* __restrict__ bi1f, const float* __restrict__ bh1f,
                             const float* __restrict__ bi1b, const float* __restrict__ bh1b,
                             const float* __restrict__ Wf, const float* __restrict__ bfv,
                             const float* __restrict__ Wb, const float* __restrict__ bbv,
                             float* __restrict__ bias0, float* __restrict__ bias1,
                             _Float16* __restrict__ wlB, float* __restrict__ blog) {
    int i = blockIdx.x * blockDim.x + threadIdx.x;
    if (i < 3200) {
        int layer = i / 1600, j = i - layer * 1600;
        int dir = j / 800, r = j - dir * 800;
        int col = dir * 800 + ((r % 200) << 2) + (r / 200);
        float v;
        if (layer == 0) v = dir ? (bi0b[r] + bh0b[r]) : (bi0f[r] + bh0f[r]);
        else            v = dir ? (bi1b[r] + bh1b[r]) : (bi1f[r] + bh1f[r]);
        (layer ? bias1 : bias0)[col] = v;
        return;
    }
    int j = i - 3200;
    if (j < 32 * WLP) {
        int n = j / WLP, k = j - n * WLP;
        float v = 0.f;
        if (n < NT_ && k < 400) v = (k < HD_) ? Wf[n * HD_ + k] : Wb[n * HD_ + (k - HD_)];
        wlB[j] = (_Float16)v;
        return;
    }
    j -= 32 * WLP;
    if (j < NT_) blog[j] = bfv[j] + bbv[j];
}

// ---------------- zero only the K-pad columns [400,416) of h0b (1 MB, not 27 MB)
__global__ __launch_bounds__(256) void k_padzero(_Float16* __restrict__ h0b) {
    int row = blockIdx.x * blockDim.x + threadIdx.x;
    if (row >= B_ * L_) return;
    _Float16* p = h0b + (size_t)row * KP1 + 400;
    *(half8*)p       = half8{0, 0, 0, 0, 0, 0, 0, 0};
    *(half8*)(p + 8) = half8{0, 0, 0, 0, 0, 0, 0, 0};
}

// ---------------- MFMA fp16 GEMM v3: C(M,1600) = A(M,Kpad) @ Bt(1600,Kpad)^T + bias
// Tile 256x64 (was 128x64): 16 MFMAs per wave per K-step between the same 2
// barriers (2x barrier amortization, m93-style tile scaling). Per wave: 64 rows
// x 64 cols, acc[4][4]. A staged row-per-thread (64 B); padded pitch-40 LDS
// (2-way-free b128 reads); coalesced LDS epilogue (pitch 72, 128 B/thread).
__global__ __launch_bounds__(256) void k_gemm16(const _Float16* __restrict__ A,
                                                const _Float16* __restrict__ Bt,
                                                const float* __restrict__ bias,
                                                _Float16* __restrict__ C,
                                                int Kpad) {
    __shared__ __align__(16) _Float16 smem[256 * 72];   // union: sA(10240)+sB(2560)=12800 | sC 18432 halves
    _Float16* sA = smem;
    _Float16* sB = smem + 256 * 40;
    const int tid = threadIdx.x;
    const int w = tid >> 6, l = tid & 63, l15 = l & 15, lq = l >> 4;
    const int m0 = blockIdx.y * 256, n0 = blockIdx.x * 64;
    const int rw = w * 64;                 // wave's row base within tile
    f32x4 acc[4][4];
    #pragma unroll
    for (int i = 0; i < 4; i++)
        #pragma unroll
        for (int j = 0; j < 4; j++) acc[i][j] = f32x4{0.f, 0.f, 0.f, 0.f};

    for (int k0 = 0; k0 < Kpad; k0 += 32) {
        {
            const _Float16* ap = A + (size_t)(m0 + tid) * Kpad + k0;
            *(half8*)&sA[tid * 40 + 0]  = *(const half8*)(ap + 0);
            *(half8*)&sA[tid * 40 + 8]  = *(const half8*)(ap + 8);
            *(half8*)&sA[tid * 40 + 16] = *(const half8*)(ap + 16);
            *(half8*)&sA[tid * 40 + 24] = *(const half8*)(ap + 24);
        }
        {
            int n = tid >> 2, k8 = (tid & 3) << 3;
            *(half8*)&sB[n * 40 + k8] = *(const half8*)&Bt[(size_t)(n0 + n) * Kpad + k0 + k8];
        }
        __syncthreads();
        half8 aF[4], bF[4];
        #pragma unroll
        for (int i = 0; i < 4; i++) aF[i] = *(const half8*)&sA[(rw + i * 16 + l15) * 40 + lq * 8];
        #pragma unroll
        for (int j = 0; j < 4; j++) bF[j] = *(const half8*)&sB[(j * 16 + l15) * 40 + lq * 8];
        #pragma unroll
        for (int i = 0; i < 4; i++)
            #pragma unroll
            for (int j = 0; j < 4; j++)
                acc[i][j] = __builtin_amdgcn_mfma_f32_16x16x32_f16(aF[i], bF[j], acc[i][j], 0, 0, 0);
        __syncthreads();
    }

    // ---- epilogue: acc (+bias, fp16) -> LDS tile [256][72] -> coalesced write
    #pragma unroll
    for (int j = 0; j < 4; j++) {
        int nl = j * 16 + l15;
        float bv = bias[n0 + nl];
        #pragma unroll
        for (int i = 0; i < 4; i++) {
            int row = rw + i * 16 + lq * 4;
            #pragma unroll
            for (int r = 0; r < 4; r++)
                smem[(row + r) * 72 + nl] = (_Float16)(acc[i][j][r] + bv);
        }
    }
    __syncthreads();
    {
        const _Float16* src = &smem[tid * 72];
        _Float16* dst = C + (size_t)(m0 + tid) * 1600 + n0;
        #pragma unroll
        for (int k = 0; k < 8; k++)
            *(half8*)(dst + k * 8) = *(const half8*)(src + k * 8);
    }
}

// ---------------- MFMA LSTM scan v10 (measured best: ~450-458 us/dispatch @ SG=4)
// Session ledger: per-step ~4240 cyc is invariant to barrier semantics (v7),
// manual hF pipelining (v8, hurt), SG=16 x3 delivery variants (v11-13, hurt),
// occupancy 2x (v14, neutral), gD-hop removal (v15, hurt). The gD round-trip
// keeps gate loads 1-per-lane coalesced + nonlin wave-wide -- do not remove.
__global__ __launch_bounds__(512) void k_scan10(const _Float16* __restrict__ gates,
                                                const float* __restrict__ Whh_f,
                                                const float* __restrict__ Whh_b,
                                                const int* __restrict__ seq_len,
                                                const int* __restrict__ perm,
                                                _Float16* __restrict__ hout, int ldH) {
    const int dir = blockIdx.x & 1;
    const int b0  = (blockIdx.x >> 1) * SG;
    const int tid = threadIdx.x;
    const int w   = tid >> 6;
    const int l   = tid & 63;
    const int l15 = l & 15;
    const int lq  = l >> 4;

    __shared__ __align__(16) _Float16 hA[2][16 * 232];   // ping-pong h state [p][m*232+k]
    __shared__ __align__(16) _Float16 bEx[2 * 7 * 512];  // W-frags tiles 48,49 (waves 0,1)
    __shared__ __align__(16) float    gD[8 * 448];       // per-wave gate sums [w*448 + cell*4 + g]
    __shared__ int ssl[SG];
    __shared__ int spb[SG];

    const float* W = dir ? Whh_b : Whh_f;
    const int nT = (w < 2) ? 7 : 6;
    const int nCell = nT * 16;          // cells owned by this wave

    // resident W-fragments (A-operand layout): 6 register tiles + tiles 48/49 in LDS
    half8 Breg[6][7];
    #pragma unroll
    for (int i = 0; i < 6; i++) {
        int n  = (w * 6 + i) * 16 + l15;
        int jh = n >> 2, g = n & 3;
        const float* Wr = W + (size_t)(g * 200 + jh) * 200;
        #pragma unroll
        for (int kt = 0; kt < 7; kt++) {
            int k0 = kt * 32 + lq * 8;
            half8 f;
            #pragma unroll
            for (int j = 0; j < 8; j++) {
                int k = k0 + j;
                f[j] = (k < 200) ? (_Float16)Wr[k] : (_Float16)0.f;
            }
            Breg[i][kt] = f;
        }
    }
    if (w < 2) {
        int n  = (48 + w) * 16 + l15;
        int jh = n >> 2, g = n & 3;
        const float* Wr = W + (size_t)(g * 200 + jh) * 200;
        for (int kt = 0; kt < 7; kt++) {
            int k0 = kt * 32 + lq * 8;
            half8 f;
            for (int j = 0; j < 8; j++) {
                int k = k0 + j;
                f[j] = (k < 200) ? (_Float16)Wr[k] : (_Float16)0.f;
            }
            *(half8*)&bEx[(w * 7 + kt) * 512 + l * 8] = f;
        }
    }
    for (int i = tid; i < 2 * 16 * 232; i += 512) (&hA[0][0])[i] = (_Float16)0.f;
    if (tid < SG) {
        int ob = perm[b0 + tid];
        spb[tid] = ob;
        ssl[tid] = seq_len[ob];
    }

    // writeback lane identity: lane v writes 4B of h row m_st
    const int  v    = tid;
    const bool stv  = v < 400;
    const int  m_st = v / 100;
    const int  u_st = v - m_st * 100;

    // nonlinearity cell identities: lane handles cells cA = l, cB = l + 64 (wave-local)
    const int cA = l;
    const int iA = cA >> 4, qA = (cA >> 2) & 3, mA = cA & 3;
    const int tgA = (iA < 6) ? (w * 6 + iA) : (48 + w);
    const int hcA = tgA * 4 + qA;
    const int cB = l + 64;
    const int iB = cB >> 4, qB = (cB >> 2) & 3, mB = cB & 3;
    const bool vB = cB < nCell;
    const int tgB = (iB < 6) ? (w * 6 + iB) : (48 + w);
    const int hcB = tgB * 4 + qB;
    float csA = 0.f, csB = 0.f;

    __syncthreads();   // ssl/spb + zeroed hA + bEx visible

    const int slmax = max(max(ssl[0], ssl[1]), max(ssl[2], ssl[3]));

    // per-cell gate pointers and seq lens (recurrence-independent addresses)
    const int slA = ssl[mA];
    const int slB = ssl[mB];
    const int slb_st = stv ? ssl[m_st] : 0;
    const _Float16* gA_base = gates + ((size_t)spb[mA] * L_) * 1600 + dir * 800 + 4 * hcA;
    const _Float16* gB_base = gates + ((size_t)spb[mB] * L_) * 1600 + dir * 800 + 4 * hcB;
    _Float16* hout_base = stv ? (hout + (size_t)spb[m_st] * L_ * ldH + dir * HD_ + 2 * u_st)
                              : hout;

    auto rowOf = [&](int t, int sl) -> int {
        return dir ? ((t < sl) ? sl - 1 - t : t) : t;
    };

    // depth-2 register prefetch of input gates (named regs, static indexing)
    half4 gA0, gA1, gB0, gB1;
    gA0 = *(const half4*)(gA_base + (size_t)rowOf(0, slA) * 1600);
    gA1 = *(const half4*)(gA_base + (size_t)rowOf(1, slA) * 1600);
    if (vB) {
        gB0 = *(const half4*)(gB_base + (size_t)rowOf(0, slB) * 1600);
        gB1 = *(const half4*)(gB_base + (size_t)rowOf(1, slB) * 1600);
    }

    const f32x4 Cz = {0.f, 0.f, 0.f, 0.f};
    for (int t = 0; t < slmax; t++) {
        const int p = t & 1;

        // coalesced writeback of h(t-1) from hA[p]: 400 lanes x 1 dword (never drained)
        if (t > 0 && stv) {
            int tp = t - 1;
            int row = dir ? ((tp < slb_st) ? slb_st - 1 - tp : tp) : tp;
            unsigned int val = (tp < slb_st) ? *(const unsigned int*)&hA[p][m_st * 232 + 2 * u_st] : 0u;
            *(unsigned int*)(hout_base + (size_t)row * ldH) = val;
        }

        // MFMA: D = W @ h(t-1)^T  (A = W-frag, B = h-frag; D col = batch, row = 4*jh+gate)
        f32x4 C[7];
        #pragma unroll
        for (int i = 0; i < 7; i++) C[i] = Cz;
        #pragma unroll
        for (int kt = 0; kt < 7; kt++) {
            half8 hF = *(const half8*)&hA[p][l15 * 232 + kt * 32 + lq * 8];
            #pragma unroll
            for (int i = 0; i < 6; i++)
                C[i] = __builtin_amdgcn_mfma_f32_16x16x32_f16(Breg[i][kt], hF, C[i], 0, 0, 0);
            if (w < 2) {
                half8 bF = *(const half8*)&bEx[(w * 7 + kt) * 512 + l * 8];
                C[6] = __builtin_amdgcn_mfma_f32_16x16x32_f16(bF, hF, C[6], 0, 0, 0);
            }
        }

        // redistribute: active lanes (l15<4) hold 4 gates of cell (tile i, q=lq, m=l15)
        if (l15 < 4) {
            #pragma unroll
            for (int i = 0; i < 6; i++)
                *(f32x4*)&gD[w * 448 + (i * 16 + lq * 4 + l15) * 4] = C[i];
            if (w < 2)
                *(f32x4*)&gD[w * 448 + (6 * 16 + lq * 4 + l15) * 4] = C[6];
        }

        // nonlinearity on all 64 lanes (same-wave LDS, no barrier)
        {
            f32x4 gv = *(const f32x4*)&gD[w * 448 + cA * 4];
            float xi = gv[0] + (float)gA0[0];
            float xf = gv[1] + (float)gA0[1];
            float xg = gv[2] + (float)gA0[2];
            float xo = gv[3] + (float)gA0[3];
            float cn = sigm_(xf) * csA + sigm_(xi) * tanh_(xg);
            csA = cn;
            hA[1 - p][mA * 232 + hcA] = (_Float16)(sigm_(xo) * tanh_(cn));
        }
        if (vB) {
            f32x4 gv = *(const f32x4*)&gD[w * 448 + cB * 4];
            float xi = gv[0] + (float)gB0[0];
            float xf = gv[1] + (float)gB0[1];
            float xg = gv[2] + (float)gB0[2];
            float xo = gv[3] + (float)gB0[3];
            float cn = sigm_(xf) * csB + sigm_(xi) * tanh_(xg);
            csB = cn;
            hA[1 - p][mB * 232 + hcB] = (_Float16)(sigm_(xo) * tanh_(cn));
        }

        // rotate prefetch regs and issue loads for t+2 (consumed ~2 steps later)
        gA0 = gA1;
        gB0 = gB1;
        if (t + 2 < L_) {
            gA1 = *(const half4*)(gA_base + (size_t)rowOf(t + 2, slA) * 1600);
            if (vB) gB1 = *(const half4*)(gB_base + (size_t)rowOf(t + 2, slB) * 1600);
        }

        barrier_lgkm();   // LDS-only drain; vmcnt stays in flight
    }
    // epilogue 1: write back h(slmax-1) from hA[slmax&1]
    if (stv) {
        int tp = slmax - 1;
        int row = dir ? ((tp < slb_st) ? slb_st - 1 - tp : tp) : tp;
        unsigned int val = (tp < slb_st) ? *(const unsigned int*)&hA[slmax & 1][m_st * 232 + 2 * u_st] : 0u;
        *(unsigned int*)(hout_base + (size_t)row * ldH) = val;
    }
    // epilogue 2: zero-fill rows [slmax, L)
    if (stv) {
        for (int tp = slmax; tp < L_; tp++)
            *(unsigned int*)(hout_base + (size_t)tp * ldH) = 0u;
    }
}

// ---------------- logits v2 (MFMA): (B*L,18) = h1(B*L,400 f16) @ wlB^T + blog
__global__ __launch_bounds__(256) void k_logits(const _Float16* __restrict__ h1,
                                                const _Float16* __restrict__ wlB,
                                                const float* __restrict__ blog,
                                                float* __restrict__ logits) {
    __shared__ __align__(16) _Float16 sW[32 * WLP];
    const int tid = threadIdx.x;
    const int w = tid >> 6, l = tid & 63, l15 = l & 15, lq = l >> 4;
    for (int i = tid; i < 32 * WLP / 8; i += 256)
        ((half8*)sW)[i] = ((const half8*)wlB)[i];
    __syncthreads();

    const int m0 = blockIdx.x * 64 + w * 16;
    const half8 hz = {0, 0, 0, 0, 0, 0, 0, 0};
    f32x4 acc0 = {0.f, 0.f, 0.f, 0.f}, acc1 = {0.f, 0.f, 0.f, 0.f};
    const _Float16* arow = h1 + (size_t)(m0 + l15) * 400;
    #pragma unroll
    for (int kt = 0; kt < 13; kt++) {
        int col = kt * 32 + lq * 8;
        half8 aF = (col < 400) ? *(const half8*)(arow + col) : hz;
        half8 bF0 = *(const half8*)&sW[l15 * WLP + col];
        half8 bF1 = *(const half8*)&sW[(16 + l15) * WLP + col];
        acc0 = __builtin_amdgcn_mfma_f32_16x16x32_f16(aF, bF0, acc0, 0, 0, 0);
        acc1 = __builtin_amdgcn_mfma_f32_16x16x32_f16(aF, bF1, acc1, 0, 0, 0);
    }
    {
        int n = l15;
        float bv = blog[n];
        #pragma unroll
        for (int r = 0; r < 4; r++)
            logits[(size_t)(m0 + lq * 4 + r) * NT_ + n] = acc0[r] + bv;
    }
    if (16 + l15 < NT_) {
        int n = 16 + l15;
        float bv = blog[n];
        #pragma unroll
        for (int r = 0; r < 4; r++)
            logits[(size_t)(m0 + lq * 4 + r) * NT_ + n] = acc1[r] + bv;
    }
}

// ---------------- CRF NLL per batch row (54-lane-parallel LSE, single wave)
__global__ __launch_bounds__(64) void k_crf(const float* __restrict__ logits,
                                            const int* __restrict__ target,
                                            const int* __restrict__ seq_len,
                                            const float* __restrict__ trans,
                                            float* __restrict__ out) {
    int b = blockIdx.x, tid = threadIdx.x;
    __shared__ float alpha[NT_];
    int sl = seq_len[b];
    const float* lg = logits + (size_t)b * L_ * NT_;
    const int* tg = target + (size_t)b * L_;

    const bool act = tid < 54;
    const int c = tid / 18, j = tid - c * 18;

    float Tl[6];
    #pragma unroll
    for (int k = 0; k < 6; k++)
        Tl[k] = act ? trans[(6 * c + k) * NT_ + j] : 0.f;

    float gacc = 0.f;
    for (int t = tid; t < L_; t += 64) {
        if (t < sl) {
            gacc += lg[t * NT_ + tg[t]];
            if (t >= 1) gacc += trans[tg[t - 1] * NT_ + tg[t]];
        }
    }
    #pragma unroll
    for (int off = 32; off; off >>= 1) gacc += __shfl_down(gacc, off);
    float gold = __shfl(gacc, 0);

    if (tid < NT_) alpha[tid] = lg[tid];

    const int src1 = (c < 2) ? tid + 18 : tid - 36;
    const int src2 = (c == 0) ? tid + 36 : tid - 18;

    for (int t = 1; t < sl; t++) {
        float m = -1e30f, s = 0.f;
        if (act) {
            float v0 = alpha[6 * c + 0] + Tl[0];
            float v1 = alpha[6 * c + 1] + Tl[1];
            float v2 = alpha[6 * c + 2] + Tl[2];
            float v3 = alpha[6 * c + 3] + Tl[3];
            float v4 = alpha[6 * c + 4] + Tl[4];
            float v5 = alpha[6 * c + 5] + Tl[5];
            m = fmaxf(fmaxf(fmaxf(v0, v1), fmaxf(v2, v3)), fmaxf(v4, v5));
            s = __expf(v0 - m) + __expf(v1 - m) + __expf(v2 - m) +
                __expf(v3 - m) + __expf(v4 - m) + __expf(v5 - m);
        }
        float m1 = __shfl(m, src1), s1 = __shfl(s, src1);
        float m2 = __shfl(m, src2), s2 = __shfl(s, src2);
        if (act && c == 0) {
            float M = fmaxf(m, fmaxf(m1, m2));
            float S = s * __expf(m - M) + s1 * __expf(m1 - M) + s2 * __expf(m2 - M);
            alpha[j] = M + __logf(S) + lg[t * NT_ + j];
        }
    }
    if (tid == 0) {
        float mx = -1e30f;
        for (int i = 0; i < NT_; i++) mx = fmaxf(mx, alpha[i]);
        float s = 0.f;
        for (int i = 0; i < NT_; i++) s += __expf(alpha[i] - mx);
        out[b] = (mx + __logf(s)) - gold;
    }
}

extern "C" void kernel_launch(void* const* d_in, const int* in_sizes, int n_in,
                              void* d_out, int out_size, void* d_ws, size_t ws_size,
                              hipStream_t stream) {
    const int*   words  = (const int*)d_in[0];
    const int*   caps   = (const int*)d_in[1];
    const int*   seq    = (const int*)d_in[2];
    const int*   target = (const int*)d_in[3];
    const float* wemb   = (const float*)d_in[4];
    const float* cemb   = (const float*)d_in[5];
    const float* Wih0f  = (const float*)d_in[6];
    const float* Whh0f  = (const float*)d_in[7];
    const float* bih0f  = (const float*)d_in[8];
    const float* bhh0f  = (const float*)d_in[9];
    const float* Wih0b  = (const float*)d_in[10];
    const float* Whh0b  = (const float*)d_in[11];
    const float* bih0b  = (const float*)d_in[12];
    const float* bhh0b  = (const float*)d_in[13];
    const float* Wih1f  = (const float*)d_in[14];
    const float* Whh1f  = (const float*)d_in[15];
    const float* bih1f  = (const float*)d_in[16];
    const float* bhh1f  = (const float*)d_in[17];
    const float* Wih1b  = (const float*)d_in[18];
    const float* Whh1b  = (const float*)d_in[19];
    const float* bih1b  = (const float*)d_in[20];
    const float* bhh1b  = (const float*)d_in[21];
    const float* Wf     = (const float*)d_in[22];
    const float* bfv    = (const float*)d_in[23];
    const float* Wb     = (const float*)d_in[24];
    const float* bbv    = (const float*)d_in[25];
    const float* trans  = (const float*)d_in[26];

    char* base = (char*)d_ws;
    _Float16* gatesH = (_Float16*)(base + 0);                 // 104,857,600 B (32768x1600)
    _Float16* xbuf   = (_Float16*)(base + 104857600);         // 10,485,760 B (32768x160)
    _Float16* h0b    = (_Float16*)(base + 115343360);         // 27,262,976 B (32768x416)
    _Float16* h1b    = xbuf;  // 26,214,400 B needed; xbuf+h0 region dead by then
    float* logitsb   = (float*)(base + 142606336);            // 2,359,296 B
    _Float16* wihT0  = (_Float16*)(base + 144965632);         // 512,000 B (1600x160)
    _Float16* wihT1  = (_Float16*)(base + 145477632);         // 1,331,200 B (1600x416)
    float* bias0     = (float*)(base + 146808832);            // 6,400 B
    float* bias1     = (float*)(base + 146815232);            // 6,400 B
    _Float16* wlB    = (_Float16*)(base + 146821632);         // 27,136 B (32xWLP fp16)
    float* blog      = (float*)(base + 146850432);            // 128 B
    int*   permb     = (int*)(base + 146850560);              // 512 B

    // --- fused weight prep + sort
    {
        int totalW = 2 * N_L0 + 2 * N_L1;   // 921,600
        k_prep_wih<<<(totalW + 255) / 256, 256, 0, stream>>>(Wih0f, Wih0b, Wih1f, Wih1b,
                                                             wihT0, wihT1);
        int totalS = 3200 + 32 * WLP + NT_;
        k_prep_small<<<(totalS + 255) / 256, 256, 0, stream>>>(bih0f, bhh0f, bih0b, bhh0b,
                                                               bih1f, bhh1f, bih1b, bhh1b,
                                                               Wf, bfv, Wb, bbv,
                                                               bias0, bias1, wlB, blog);
    }
    k_sortperm<<<1, 128, 0, stream>>>(seq, permb);

    // --- embeddings (fp16, padded)
    k_embed<<<B_ * L_, 128, 0, stream>>>(words, caps, wemb, cemb, xbuf);

    // zero only h0's K-pad cols [400,416) (scan writes all of cols [0,400))
    k_padzero<<<(B_ * L_ + 255) / 256, 256, 0, stream>>>(h0b);

    // --- layer 0
    k_gemm16<<<dim3(25, 128), 256, 0, stream>>>(xbuf, wihT0, bias0, gatesH, KP0);
    k_scan10<<<(B_ / SG) * 2, 512, 0, stream>>>(gatesH, Whh0f, Whh0b, seq, permb, h0b, KP1);

    // --- layer 1
    k_gemm16<<<dim3(25, 128), 256, 0, stream>>>(h0b, wihT1, bias1, gatesH, KP1);
    k_scan10<<<(B_ / SG) * 2, 512, 0, stream>>>(gatesH, Whh1f, Whh1b, seq, permb, h1b, 400);

    // --- logits + CRF
    k_logits<<<(B_ * L_) / 64, 256, 0, stream>>>(h1b, wlB, blog, logitsb);
    k_crf<<<B_, 64, 0, stream>>>(logitsb, target, seq, trans, (float*)d_out);
}

// Round 15
// 1354.720 us; speedup vs baseline: 1.0174x; 1.0174x over previous
//
#include <hip/hip_runtime.h>
#include <math.h>

#define B_   128
#define L_   256
#define DW_  100
#define DC_  30
#define HD_  200
#define NT_  18
#define SG   4     // batches per scan block (v10 proven config)
#define KP0  160   // padded K for layer-0 GEMM (130 -> 160)
#define KP1  416   // padded K for layer-1 GEMM (400 -> 416)
#define WLP  424   // wlB pitch in halves (16B-aligned, 8-bank spread)

typedef _Float16 half8 __attribute__((ext_vector_type(8)));
typedef _Float16 half4 __attribute__((ext_vector_type(4)));
typedef float    f32x4 __attribute__((ext_vector_type(4)));

__device__ __forceinline__ float frcp_(float x) { return __builtin_amdgcn_rcpf(x); }
__device__ __forceinline__ float sigm_(float x) { return frcp_(1.0f + __expf(-x)); }
__device__ __forceinline__ float tanh_(float x) { return 1.0f - 2.0f * frcp_(1.0f + __expf(2.0f * x)); }

// barrier that does NOT drain vmcnt: LDS visibility only.
__device__ __forceinline__ void barrier_lgkm() {
    asm volatile("s_waitcnt lgkmcnt(0)" ::: "memory");
    __builtin_amdgcn_s_barrier();
    asm volatile("" ::: "memory");
}

// ---------------- seq_len rank sort -> perm (ascending), one block
__global__ __launch_bounds__(128) void k_sortperm(const int* __restrict__ seq_len,
                                                  int* __restrict__ perm) {
    __shared__ int s[B_];
    int i = threadIdx.x;
    s[i] = seq_len[i];
    __syncthreads();
    int key = s[i], r = 0;
    for (int j = 0; j < B_; j++) {
        int v = s[j];
        r += (v < key) || (v == key && j < i);
    }
    perm[r] = i;
}

// ---------------- embedding gather -> fp16 x (B*L, KP0), pads zeroed
__global__ void k_embed(const int* __restrict__ words, const int* __restrict__ caps,
                        const float* __restrict__ wemb, const float* __restrict__ cemb,
                        _Float16* __restrict__ x) {
    int pos = blockIdx.x;
    int w = words[pos], c = caps[pos];
    _Float16* xp = x + (size_t)pos * KP0;
    for (int t = threadIdx.x; t < KP0; t += blockDim.x) {
        float v = 0.f;
        if (t < DW_) v = wemb[(size_t)w * DW_ + t];
        else if (t < DW_ + DC_) v = cemb[(size_t)c * DC_ + (t - DW_)];
        xp[t] = (_Float16)v;
    }
}

// ---------------- fused W_ih prep for all 4 (layer,dir) weight blocks.
#define N_L0 (800 * KP0)     // per-direction element count, layer 0
#define N_L1 (800 * KP1)     // per-direction element count, layer 1
__global__ void k_prep_wih(const float* __restrict__ Wih0f, const float* __restrict__ Wih0b,
                           const float* __restrict__ Wih1f, const float* __restrict__ Wih1b,
                           _Float16* __restrict__ wihT0, _Float16* __restrict__ wihT1) {
    int i = blockIdx.x * blockDim.x + threadIdx.x;
    const float* src;
    _Float16* dst;
    int K, Kpad, colOff, idx;
    if (i < 2 * N_L0) {
        int which = i / N_L0;            // 0 = fwd, 1 = bwd
        idx = i - which * N_L0;
        src = which ? Wih0b : Wih0f;
        dst = wihT0; K = 130; Kpad = KP0; colOff = which * 800;
    } else {
        int j = i - 2 * N_L0;
        if (j >= 2 * N_L1) return;
        int which = j / N_L1;
        idx = j - which * N_L1;
        src = which ? Wih1b : Wih1f;
        dst = wihT1; K = 400; Kpad = KP1; colOff = which * 800;
    }
    int r = idx / Kpad, k = idx - r * Kpad;
    int jh = r % 200, g = r / 200;
    int col = colOff + (jh << 2) + g;
    dst[(size_t)col * Kpad + k] = (k < K) ? (_Float16)src[(size_t)r * K + k] : (_Float16)0.f;
}

// ---------------- fused small prep: bias0, bias1, wlB, blog in one launch.
__global__ void k_prep_small(const float* __restrict__ bi0f, const float* __restrict__ bh0f,
                             const float* __restrict__ bi0b, const float* __restrict__ bh0b,
                             const float* __restrict__ bi1f, const float* __restrict__ bh1f,
                             const float* __restrict__ bi1b, const float* __restrict__ bh1b,
                             const float* __restrict__ Wf, const float* __restrict__ bfv,
                             const float* __restrict__ Wb, const float* __restrict__ bbv,
                             float* __restrict__ bias0, float* __restrict__ bias1,
                             _Float16* __restrict__ wlB, float* __restrict__ blog) {
    int i = blockIdx.x * blockDim.x + threadIdx.x;
    if (i < 3200) {
        int layer = i / 1600, j = i - layer * 1600;
        int dir = j / 800, r = j - dir * 800;
        int col = dir * 800 + ((r % 200) << 2) + (r / 200);
        float v;
        if (layer == 0) v = dir ? (bi0b[r] + bh0b[r]) : (bi0f[r] + bh0f[r]);
        else            v = dir ? (bi1b[r] + bh1b[r]) : (bi1f[r] + bh1f[r]);
        (layer ? bias1 : bias0)[col] = v;
        return;
    }
    int j = i - 3200;
    if (j < 32 * WLP) {
        int n = j / WLP, k = j - n * WLP;
        float v = 0.f;
        if (n < NT_ && k < 400) v = (k < HD_) ? Wf[n * HD_ + k] : Wb[n * HD_ + (k - HD_)];
        wlB[j] = (_Float16)v;
        return;
    }
    j -= 32 * WLP;
    if (j < NT_) blog[j] = bfv[j] + bbv[j];
}

// ---------------- zero only the K-pad columns [400,416) of h0b (1 MB, not 27 MB)
__global__ __launch_bounds__(256) void k_padzero(_Float16* __restrict__ h0b) {
    int row = blockIdx.x * blockDim.x + threadIdx.x;
    if (row >= B_ * L_) return;
    _Float16* p = h0b + (size_t)row * KP1 + 400;
    *(half8*)p       = half8{0, 0, 0, 0, 0, 0, 0, 0};
    *(half8*)(p + 8) = half8{0, 0, 0, 0, 0, 0, 0, 0};
}

// ---------------- MFMA fp16 GEMM: C(M,1600) = A(M,Kpad) @ Bt(1600,Kpad)^T + bias
// 128x64 tile (R13 proven best; 256-tile variant was slightly worse, R14).
// LDS-staged coalesced C-writeback epilogue.
__global__ __launch_bounds__(256) void k_gemm16(const _Float16* __restrict__ A,
                                                const _Float16* __restrict__ Bt,
                                                const float* __restrict__ bias,
                                                _Float16* __restrict__ C,
                                                int Kpad) {
    __shared__ __align__(16) _Float16 smem[128 * 72];   // union: sA(5120)+sB(2560) | sC(9216)
    _Float16* sA = smem;
    _Float16* sB = smem + 128 * 40;
    const int tid = threadIdx.x;
    const int w = tid >> 6, l = tid & 63, l15 = l & 15, lq = l >> 4;
    const int m0 = blockIdx.y * 128, n0 = blockIdx.x * 64;
    const int rw = (w >> 1) * 64, cw = (w & 1) * 32;
    f32x4 acc[4][2];
    #pragma unroll
    for (int i = 0; i < 4; i++)
        #pragma unroll
        for (int j = 0; j < 2; j++) acc[i][j] = f32x4{0.f, 0.f, 0.f, 0.f};

    for (int k0 = 0; k0 < Kpad; k0 += 32) {
        {
            int m = tid >> 1, c = (tid & 1) << 4;
            const _Float16* ap = A + (size_t)(m0 + m) * Kpad + k0 + c;
            *(half8*)&sA[m * 40 + c]     = *(const half8*)ap;
            *(half8*)&sA[m * 40 + c + 8] = *(const half8*)(ap + 8);
        }
        {
            int n = tid >> 2, k8 = (tid & 3) << 3;
            *(half8*)&sB[n * 40 + k8] = *(const half8*)&Bt[(size_t)(n0 + n) * Kpad + k0 + k8];
        }
        __syncthreads();
        half8 aF[4], bF[2];
        #pragma unroll
        for (int i = 0; i < 4; i++) aF[i] = *(const half8*)&sA[(rw + i * 16 + l15) * 40 + lq * 8];
        #pragma unroll
        for (int j = 0; j < 2; j++) bF[j] = *(const half8*)&sB[(cw + j * 16 + l15) * 40 + lq * 8];
        #pragma unroll
        for (int i = 0; i < 4; i++)
            #pragma unroll
            for (int j = 0; j < 2; j++)
                acc[i][j] = __builtin_amdgcn_mfma_f32_16x16x32_f16(aF[i], bF[j], acc[i][j], 0, 0, 0);
        __syncthreads();
    }

    // ---- epilogue: acc (+bias, fp16) -> LDS tile [128][72] -> coalesced write
    #pragma unroll
    for (int j = 0; j < 2; j++) {
        int nl = cw + j * 16 + l15;
        float bv = bias[n0 + nl];
        #pragma unroll
        for (int i = 0; i < 4; i++) {
            int row = rw + i * 16 + lq * 4;
            #pragma unroll
            for (int r = 0; r < 4; r++)
                smem[(row + r) * 72 + nl] = (_Float16)(acc[i][j][r] + bv);
        }
    }
    __syncthreads();
    {
        int row = tid >> 1, hh = tid & 1;
        const _Float16* src = &smem[row * 72 + hh * 32];
        _Float16* dst = C + (size_t)(m0 + row) * 1600 + n0 + hh * 32;
        #pragma unroll
        for (int k = 0; k < 4; k++)
            *(half8*)(dst + k * 8) = *(const half8*)(src + k * 8);
    }
}

// ---------------- MFMA LSTM scan v10 (measured best: ~450-458 us/dispatch @ SG=4)
// Session ledger: per-step ~4240 cyc is invariant to barrier semantics (v7),
// manual hF pipelining (v8, hurt), SG=16 x3 delivery variants (v11-13, hurt),
// occupancy 2x (v14, neutral), gD-hop removal (v15, hurt). The gD round-trip
// keeps gate loads 1-per-lane coalesced + nonlin wave-wide -- do not remove.
// Remaining headroom is algorithmic (time-parallel scan), not polish.
__global__ __launch_bounds__(512) void k_scan10(const _Float16* __restrict__ gates,
                                                const float* __restrict__ Whh_f,
                                                const float* __restrict__ Whh_b,
                                                const int* __restrict__ seq_len,
                                                const int* __restrict__ perm,
                                                _Float16* __restrict__ hout, int ldH) {
    const int dir = blockIdx.x & 1;
    const int b0  = (blockIdx.x >> 1) * SG;
    const int tid = threadIdx.x;
    const int w   = tid >> 6;
    const int l   = tid & 63;
    const int l15 = l & 15;
    const int lq  = l >> 4;

    __shared__ __align__(16) _Float16 hA[2][16 * 232];   // ping-pong h state [p][m*232+k]
    __shared__ __align__(16) _Float16 bEx[2 * 7 * 512];  // W-frags tiles 48,49 (waves 0,1)
    __shared__ __align__(16) float    gD[8 * 448];       // per-wave gate sums [w*448 + cell*4 + g]
    __shared__ int ssl[SG];
    __shared__ int spb[SG];

    const float* W = dir ? Whh_b : Whh_f;
    const int nT = (w < 2) ? 7 : 6;
    const int nCell = nT * 16;          // cells owned by this wave

    // resident W-fragments (A-operand layout): 6 register tiles + tiles 48/49 in LDS
    half8 Breg[6][7];
    #pragma unroll
    for (int i = 0; i < 6; i++) {
        int n  = (w * 6 + i) * 16 + l15;
        int jh = n >> 2, g = n & 3;
        const float* Wr = W + (size_t)(g * 200 + jh) * 200;
        #pragma unroll
        for (int kt = 0; kt < 7; kt++) {
            int k0 = kt * 32 + lq * 8;
            half8 f;
            #pragma unroll
            for (int j = 0; j < 8; j++) {
                int k = k0 + j;
                f[j] = (k < 200) ? (_Float16)Wr[k] : (_Float16)0.f;
            }
            Breg[i][kt] = f;
        }
    }
    if (w < 2) {
        int n  = (48 + w) * 16 + l15;
        int jh = n >> 2, g = n & 3;
        const float* Wr = W + (size_t)(g * 200 + jh) * 200;
        for (int kt = 0; kt < 7; kt++) {
            int k0 = kt * 32 + lq * 8;
            half8 f;
            for (int j = 0; j < 8; j++) {
                int k = k0 + j;
                f[j] = (k < 200) ? (_Float16)Wr[k] : (_Float16)0.f;
            }
            *(half8*)&bEx[(w * 7 + kt) * 512 + l * 8] = f;
        }
    }
    for (int i = tid; i < 2 * 16 * 232; i += 512) (&hA[0][0])[i] = (_Float16)0.f;
    if (tid < SG) {
        int ob = perm[b0 + tid];
        spb[tid] = ob;
        ssl[tid] = seq_len[ob];
    }

    // writeback lane identity: lane v writes 4B of h row m_st
    const int  v    = tid;
    const bool stv  = v < 400;
    const int  m_st = v / 100;
    const int  u_st = v - m_st * 100;

    // nonlinearity cell identities: lane handles cells cA = l, cB = l + 64 (wave-local)
    const int cA = l;
    const int iA = cA >> 4, qA = (cA >> 2) & 3, mA = cA & 3;
    const int tgA = (iA < 6) ? (w * 6 + iA) : (48 + w);
    const int hcA = tgA * 4 + qA;
    const int cB = l + 64;
    const int iB = cB >> 4, qB = (cB >> 2) & 3, mB = cB & 3;
    const bool vB = cB < nCell;
    const int tgB = (iB < 6) ? (w * 6 + iB) : (48 + w);
    const int hcB = tgB * 4 + qB;
    float csA = 0.f, csB = 0.f;

    __syncthreads();   // ssl/spb + zeroed hA + bEx visible

    const int slmax = max(max(ssl[0], ssl[1]), max(ssl[2], ssl[3]));

    // per-cell gate pointers and seq lens (recurrence-independent addresses)
    const int slA = ssl[mA];
    const int slB = ssl[mB];
    const int slb_st = stv ? ssl[m_st] : 0;
    const _Float16* gA_base = gates + ((size_t)spb[mA] * L_) * 1600 + dir * 800 + 4 * hcA;
    const _Float16* gB_base = gates + ((size_t)spb[mB] * L_) * 1600 + dir * 800 + 4 * hcB;
    _Float16* hout_base = stv ? (hout + (size_t)spb[m_st] * L_ * ldH + dir * HD_ + 2 * u_st)
                              : hout;

    auto rowOf = [&](int t, int sl) -> int {
        return dir ? ((t < sl) ? sl - 1 - t : t) : t;
    };

    // depth-2 register prefetch of input gates (named regs, static indexing)
    half4 gA0, gA1, gB0, gB1;
    gA0 = *(const half4*)(gA_base + (size_t)rowOf(0, slA) * 1600);
    gA1 = *(const half4*)(gA_base + (size_t)rowOf(1, slA) * 1600);
    if (vB) {
        gB0 = *(const half4*)(gB_base + (size_t)rowOf(0, slB) * 1600);
        gB1 = *(const half4*)(gB_base + (size_t)rowOf(1, slB) * 1600);
    }

    const f32x4 Cz = {0.f, 0.f, 0.f, 0.f};
    for (int t = 0; t < slmax; t++) {
        const int p = t & 1;

        // coalesced writeback of h(t-1) from hA[p]: 400 lanes x 1 dword (never drained)
        if (t > 0 && stv) {
            int tp = t - 1;
            int row = dir ? ((tp < slb_st) ? slb_st - 1 - tp : tp) : tp;
            unsigned int val = (tp < slb_st) ? *(const unsigned int*)&hA[p][m_st * 232 + 2 * u_st] : 0u;
            *(unsigned int*)(hout_base + (size_t)row * ldH) = val;
        }

        // MFMA: D = W @ h(t-1)^T  (A = W-frag, B = h-frag; D col = batch, row = 4*jh+gate)
        f32x4 C[7];
        #pragma unroll
        for (int i = 0; i < 7; i++) C[i] = Cz;
        #pragma unroll
        for (int kt = 0; kt < 7; kt++) {
            half8 hF = *(const half8*)&hA[p][l15 * 232 + kt * 32 + lq * 8];
            #pragma unroll
            for (int i = 0; i < 6; i++)
                C[i] = __builtin_amdgcn_mfma_f32_16x16x32_f16(Breg[i][kt], hF, C[i], 0, 0, 0);
            if (w < 2) {
                half8 bF = *(const half8*)&bEx[(w * 7 + kt) * 512 + l * 8];
                C[6] = __builtin_amdgcn_mfma_f32_16x16x32_f16(bF, hF, C[6], 0, 0, 0);
            }
        }

        // redistribute: active lanes (l15<4) hold 4 gates of cell (tile i, q=lq, m=l15)
        if (l15 < 4) {
            #pragma unroll
            for (int i = 0; i < 6; i++)
                *(f32x4*)&gD[w * 448 + (i * 16 + lq * 4 + l15) * 4] = C[i];
            if (w < 2)
                *(f32x4*)&gD[w * 448 + (6 * 16 + lq * 4 + l15) * 4] = C[6];
        }

        // nonlinearity on all 64 lanes (same-wave LDS, no barrier)
        {
            f32x4 gv = *(const f32x4*)&gD[w * 448 + cA * 4];
            float xi = gv[0] + (float)gA0[0];
            float xf = gv[1] + (float)gA0[1];
            float xg = gv[2] + (float)gA0[2];
            float xo = gv[3] + (float)gA0[3];
            float cn = sigm_(xf) * csA + sigm_(xi) * tanh_(xg);
            csA = cn;
            hA[1 - p][mA * 232 + hcA] = (_Float16)(sigm_(xo) * tanh_(cn));
        }
        if (vB) {
            f32x4 gv = *(const f32x4*)&gD[w * 448 + cB * 4];
            float xi = gv[0] + (float)gB0[0];
            float xf = gv[1] + (float)gB0[1];
            float xg = gv[2] + (float)gB0[2];
            float xo = gv[3] + (float)gB0[3];
            float cn = sigm_(xf) * csB + sigm_(xi) * tanh_(xg);
            csB = cn;
            hA[1 - p][mB * 232 + hcB] = (_Float16)(sigm_(xo) * tanh_(cn));
        }

        // rotate prefetch regs and issue loads for t+2 (consumed ~2 steps later)
        gA0 = gA1;
        gB0 = gB1;
        if (t + 2 < L_) {
            gA1 = *(const half4*)(gA_base + (size_t)rowOf(t + 2, slA) * 1600);
            if (vB) gB1 = *(const half4*)(gB_base + (size_t)rowOf(t + 2, slB) * 1600);
        }

        barrier_lgkm();   // LDS-only drain; vmcnt stays in flight
    }
    // epilogue 1: write back h(slmax-1) from hA[slmax&1]
    if (stv) {
        int tp = slmax - 1;
        int row = dir ? ((tp < slb_st) ? slb_st - 1 - tp : tp) : tp;
        unsigned int val = (tp < slb_st) ? *(const unsigned int*)&hA[slmax & 1][m_st * 232 + 2 * u_st] : 0u;
        *(unsigned int*)(hout_base + (size_t)row * ldH) = val;
    }
    // epilogue 2: zero-fill rows [slmax, L)
    if (stv) {
        for (int tp = slmax; tp < L_; tp++)
            *(unsigned int*)(hout_base + (size_t)tp * ldH) = 0u;
    }
}

// ---------------- logits v2 (MFMA): (B*L,18) = h1(B*L,400 f16) @ wlB^T + blog
__global__ __launch_bounds__(256) void k_logits(const _Float16* __restrict__ h1,
                                                const _Float16* __restrict__ wlB,
                                                const float* __restrict__ blog,
                                                float* __restrict__ logits) {
    __shared__ __align__(16) _Float16 sW[32 * WLP];
    const int tid = threadIdx.x;
    const int w = tid >> 6, l = tid & 63, l15 = l & 15, lq = l >> 4;
    for (int i = tid; i < 32 * WLP / 8; i += 256)
        ((half8*)sW)[i] = ((const half8*)wlB)[i];
    __syncthreads();

    const int m0 = blockIdx.x * 64 + w * 16;
    const half8 hz = {0, 0, 0, 0, 0, 0, 0, 0};
    f32x4 acc0 = {0.f, 0.f, 0.f, 0.f}, acc1 = {0.f, 0.f, 0.f, 0.f};
    const _Float16* arow = h1 + (size_t)(m0 + l15) * 400;
    #pragma unroll
    for (int kt = 0; kt < 13; kt++) {
        int col = kt * 32 + lq * 8;
        half8 aF = (col < 400) ? *(const half8*)(arow + col) : hz;
        half8 bF0 = *(const half8*)&sW[l15 * WLP + col];
        half8 bF1 = *(const half8*)&sW[(16 + l15) * WLP + col];
        acc0 = __builtin_amdgcn_mfma_f32_16x16x32_f16(aF, bF0, acc0, 0, 0, 0);
        acc1 = __builtin_amdgcn_mfma_f32_16x16x32_f16(aF, bF1, acc1, 0, 0, 0);
    }
    {
        int n = l15;
        float bv = blog[n];
        #pragma unroll
        for (int r = 0; r < 4; r++)
            logits[(size_t)(m0 + lq * 4 + r) * NT_ + n] = acc0[r] + bv;
    }
    if (16 + l15 < NT_) {
        int n = 16 + l15;
        float bv = blog[n];
        #pragma unroll
        for (int r = 0; r < 4; r++)
            logits[(size_t)(m0 + lq * 4 + r) * NT_ + n] = acc1[r] + bv;
    }
}

// ---------------- CRF NLL per batch row (54-lane-parallel LSE, single wave)
__global__ __launch_bounds__(64) void k_crf(const float* __restrict__ logits,
                                            const int* __restrict__ target,
                                            const int* __restrict__ seq_len,
                                            const float* __restrict__ trans,
                                            float* __restrict__ out) {
    int b = blockIdx.x, tid = threadIdx.x;
    __shared__ float alpha[NT_];
    int sl = seq_len[b];
    const float* lg = logits + (size_t)b * L_ * NT_;
    const int* tg = target + (size_t)b * L_;

    const bool act = tid < 54;
    const int c = tid / 18, j = tid - c * 18;

    float Tl[6];
    #pragma unroll
    for (int k = 0; k < 6; k++)
        Tl[k] = act ? trans[(6 * c + k) * NT_ + j] : 0.f;

    float gacc = 0.f;
    for (int t = tid; t < L_; t += 64) {
        if (t < sl) {
            gacc += lg[t * NT_ + tg[t]];
            if (t >= 1) gacc += trans[tg[t - 1] * NT_ + tg[t]];
        }
    }
    #pragma unroll
    for (int off = 32; off; off >>= 1) gacc += __shfl_down(gacc, off);
    float gold = __shfl(gacc, 0);

    if (tid < NT_) alpha[tid] = lg[tid];

    const int src1 = (c < 2) ? tid + 18 : tid - 36;
    const int src2 = (c == 0) ? tid + 36 : tid - 18;

    for (int t = 1; t < sl; t++) {
        float m = -1e30f, s = 0.f;
        if (act) {
            float v0 = alpha[6 * c + 0] + Tl[0];
            float v1 = alpha[6 * c + 1] + Tl[1];
            float v2 = alpha[6 * c + 2] + Tl[2];
            float v3 = alpha[6 * c + 3] + Tl[3];
            float v4 = alpha[6 * c + 4] + Tl[4];
            float v5 = alpha[6 * c + 5] + Tl[5];
            m = fmaxf(fmaxf(fmaxf(v0, v1), fmaxf(v2, v3)), fmaxf(v4, v5));
            s = __expf(v0 - m) + __expf(v1 - m) + __expf(v2 - m) +
                __expf(v3 - m) + __expf(v4 - m) + __expf(v5 - m);
        }
        float m1 = __shfl(m, src1), s1 = __shfl(s, src1);
        float m2 = __shfl(m, src2), s2 = __shfl(s, src2);
        if (act && c == 0) {
            float M = fmaxf(m, fmaxf(m1, m2));
            float S = s * __expf(m - M) + s1 * __expf(m1 - M) + s2 * __expf(m2 - M);
            alpha[j] = M + __logf(S) + lg[t * NT_ + j];
        }
    }
    if (tid == 0) {
        float mx = -1e30f;
        for (int i = 0; i < NT_; i++) mx = fmaxf(mx, alpha[i]);
        float s = 0.f;
        for (int i = 0; i < NT_; i++) s += __expf(alpha[i] - mx);
        out[b] = (mx + __logf(s)) - gold;
    }
}

extern "C" void kernel_launch(void* const* d_in, const int* in_sizes, int n_in,
                              void* d_out, int out_size, void* d_ws, size_t ws_size,
                              hipStream_t stream) {
    const int*   words  = (const int*)d_in[0];
    const int*   caps   = (const int*)d_in[1];
    const int*   seq    = (const int*)d_in[2];
    const int*   target = (const int*)d_in[3];
    const float* wemb   = (const float*)d_in[4];
    const float* cemb   = (const float*)d_in[5];
    const float* Wih0f  = (const float*)d_in[6];
    const float* Whh0f  = (const float*)d_in[7];
    const float* bih0f  = (const float*)d_in[8];
    const float* bhh0f  = (const float*)d_in[9];
    const float* Wih0b  = (const float*)d_in[10];
    const float* Whh0b  = (const float*)d_in[11];
    const float* bih0b  = (const float*)d_in[12];
    const float* bhh0b  = (const float*)d_in[13];
    const float* Wih1f  = (const float*)d_in[14];
    const float* Whh1f  = (const float*)d_in[15];
    const float* bih1f  = (const float*)d_in[16];
    const float* bhh1f  = (const float*)d_in[17];
    const float* Wih1b  = (const float*)d_in[18];
    const float* Whh1b  = (const float*)d_in[19];
    const float* bih1b  = (const float*)d_in[20];
    const float* bhh1b  = (const float*)d_in[21];
    const float* Wf     = (const float*)d_in[22];
    const float* bfv    = (const float*)d_in[23];
    const float* Wb     = (const float*)d_in[24];
    const float* bbv    = (const float*)d_in[25];
    const float* trans  = (const float*)d_in[26];

    char* base = (char*)d_ws;
    _Float16* gatesH = (_Float16*)(base + 0);                 // 104,857,600 B (32768x1600)
    _Float16* xbuf   = (_Float16*)(base + 104857600);         // 10,485,760 B (32768x160)
    _Float16* h0b    = (_Float16*)(base + 115343360);         // 27,262,976 B (32768x416)
    _Float16* h1b    = xbuf;  // 26,214,400 B needed; xbuf+h0 region dead by then
    float* logitsb   = (float*)(base + 142606336);            // 2,359,296 B
    _Float16* wihT0  = (_Float16*)(base + 144965632);         // 512,000 B (1600x160)
    _Float16* wihT1  = (_Float16*)(base + 145477632);         // 1,331,200 B (1600x416)
    float* bias0     = (float*)(base + 146808832);            // 6,400 B
    float* bias1     = (float*)(base + 146815232);            // 6,400 B
    _Float16* wlB    = (_Float16*)(base + 146821632);         // 27,136 B (32xWLP fp16)
    float* blog      = (float*)(base + 146850432);            // 128 B
    int*   permb     = (int*)(base + 146850560);              // 512 B

    // --- fused weight prep + sort
    {
        int totalW = 2 * N_L0 + 2 * N_L1;   // 921,600
        k_prep_wih<<<(totalW + 255) / 256, 256, 0, stream>>>(Wih0f, Wih0b, Wih1f, Wih1b,
                                                             wihT0, wihT1);
        int totalS = 3200 + 32 * WLP + NT_;
        k_prep_small<<<(totalS + 255) / 256, 256, 0, stream>>>(bih0f, bhh0f, bih0b, bhh0b,
                                                               bih1f, bhh1f, bih1b, bhh1b,
                                                               Wf, bfv, Wb, bbv,
                                                               bias0, bias1, wlB, blog);
    }
    k_sortperm<<<1, 128, 0, stream>>>(seq, permb);

    // --- embeddings (fp16, padded)
    k_embed<<<B_ * L_, 128, 0, stream>>>(words, caps, wemb, cemb, xbuf);

    // zero only h0's K-pad cols [400,416) (scan writes all of cols [0,400))
    k_padzero<<<(B_ * L_ + 255) / 256, 256, 0, stream>>>(h0b);

    // --- layer 0
    k_gemm16<<<dim3(25, 256), 256, 0, stream>>>(xbuf, wihT0, bias0, gatesH, KP0);
    k_scan10<<<(B_ / SG) * 2, 512, 0, stream>>>(gatesH, Whh0f, Whh0b, seq, permb, h0b, KP1);

    // --- layer 1
    k_gemm16<<<dim3(25, 256), 256, 0, stream>>>(h0b, wihT1, bias1, gatesH, KP1);
    k_scan10<<<(B_ / SG) * 2, 512, 0, stream>>>(gatesH, Whh1f, Whh1b, seq, permb, h1b, 400);

    // --- logits + CRF
    k_logits<<<(B_ * L_) / 64, 256, 0, stream>>>(h1b, wlB, blog, logitsb);
    k_crf<<<B_, 64, 0, stream>>>(logitsb, target, seq, trans, (float*)d_out);
}